// Round 1
// baseline (532.188 us; speedup 1.0000x reference)
//
#include <hip/hip_runtime.h>

#define NSEG 2048
#define EPS 1e-6f

// Monotonic float->uint key: preserves ordering so uint atomicMin/Max works.
__device__ __forceinline__ unsigned enc(float f) {
    unsigned u = __float_as_uint(f);
    return (u & 0x80000000u) ? ~u : (u | 0x80000000u);
}
__device__ __forceinline__ float dec(unsigned k) {
    unsigned u = (k & 0x80000000u) ? (k & 0x7FFFFFFFu) : ~k;
    return __uint_as_float(u);
}

__global__ void init_k(unsigned* __restrict__ mn_k, unsigned* __restrict__ mx_k) {
    int i = blockIdx.x * blockDim.x + threadIdx.x;
    if (i < NSEG) {
        mn_k[i] = 0xFFFFFFFFu;  // encodes +inf-ish (max key)
        mx_k[i] = 0u;           // min key
    }
}

// One thread per row (D=64 floats = 16 float4). Wave covers 64 consecutive
// rows; seg is sorted, so ~87% of waves are single-segment -> one atomic
// pair per wave after a 6-level shuffle reduction.
__global__ __launch_bounds__(256) void pass1(const float4* __restrict__ x4,
                                             const int* __restrict__ seg,
                                             unsigned* __restrict__ mn_k,
                                             unsigned* __restrict__ mx_k,
                                             int nrows) {
    int row = blockIdx.x * 256 + threadIdx.x;
    if (row >= nrows) return;
    const float4* xr = x4 + (long)row * 16;
    float lmin = INFINITY, lmax = -INFINITY;
#pragma unroll
    for (int j = 0; j < 16; ++j) {
        float4 v = xr[j];
        lmin = fminf(lmin, fminf(fminf(v.x, v.y), fminf(v.z, v.w)));
        lmax = fmaxf(lmax, fmaxf(fmaxf(v.x, v.y), fmaxf(v.z, v.w)));
    }
    int s = seg[row];
    int first = __shfl(s, 0);
    if (__all(s == first)) {
        // whole wave is one segment: cross-lane reduce, single atomic pair
#pragma unroll
        for (int off = 32; off; off >>= 1) {
            lmin = fminf(lmin, __shfl_xor(lmin, off));
            lmax = fmaxf(lmax, __shfl_xor(lmax, off));
        }
        if ((threadIdx.x & 63) == 0) {
            atomicMin(&mn_k[first], enc(lmin));
            atomicMax(&mx_k[first], enc(lmax));
        }
    } else {
        // boundary wave (rare): per-row atomics
        atomicMin(&mn_k[s], enc(lmin));
        atomicMax(&mx_k[s], enc(lmax));
    }
}

__global__ void scalek(const unsigned* __restrict__ mn_k,
                       const unsigned* __restrict__ mx_k,
                       float2* __restrict__ prm) {
    int i = blockIdx.x * blockDim.x + threadIdx.x;
    if (i < NSEG) {
        float mn = dec(mn_k[i]);
        float mx = dec(mx_k[i]);
        float2 p;
        p.x = mn;
        p.y = 1.0f / (mx - mn + EPS);
        prm[i] = p;
    }
}

// One thread per float4 element group.
__global__ __launch_bounds__(256) void pass2(const float4* __restrict__ x4,
                                             const int* __restrict__ seg,
                                             const float2* __restrict__ prm,
                                             float4* __restrict__ out4,
                                             long n4) {
    long g = (long)blockIdx.x * 256 + threadIdx.x;
    if (g >= n4) return;
    int row = (int)(g >> 4);  // 16 float4 per row
    int s = seg[row];
    float2 p = prm[s];
    float4 v = x4[g];
    float4 o;
    o.x = (v.x - p.x) * p.y;
    o.y = (v.y - p.x) * p.y;
    o.z = (v.z - p.x) * p.y;
    o.w = (v.w - p.x) * p.y;
    out4[g] = o;
}

extern "C" void kernel_launch(void* const* d_in, const int* in_sizes, int n_in,
                              void* d_out, int out_size, void* d_ws, size_t ws_size,
                              hipStream_t stream) {
    const float* x = (const float*)d_in[0];
    const int* seg = (const int*)d_in[1];
    float* out = (float*)d_out;

    const int nrows = in_sizes[1];          // N = 1,000,000
    const long n4 = (long)out_size / 4;     // float4 count = N*64/4

    // workspace layout
    unsigned* mn_k = (unsigned*)d_ws;                 // [NSEG]
    unsigned* mx_k = mn_k + NSEG;                     // [NSEG]
    float2* prm = (float2*)(mx_k + NSEG);             // [NSEG]

    init_k<<<(NSEG + 255) / 256, 256, 0, stream>>>(mn_k, mx_k);

    int blocks1 = (nrows + 255) / 256;
    pass1<<<blocks1, 256, 0, stream>>>((const float4*)x, seg, mn_k, mx_k, nrows);

    scalek<<<(NSEG + 255) / 256, 256, 0, stream>>>(mn_k, mx_k, prm);

    long blocks2 = (n4 + 255) / 256;
    pass2<<<(int)blocks2, 256, 0, stream>>>((const float4*)x, seg, prm,
                                            (float4*)out, n4);
}

// Round 3
// 472.430 us; speedup vs baseline: 1.1265x; 1.1265x over previous
//
#include <hip/hip_runtime.h>

#define NSEG 2048
#define EPS 1e-6f
#define TROWS 256              // rows per block in pass1
#define TF4 (TROWS * 16)       // float4s per block tile (4096)

typedef float nfloat4 __attribute__((ext_vector_type(4)));  // native vec for nt store

// Monotonic float->uint key: preserves ordering so uint atomicMin/Max works.
__device__ __forceinline__ unsigned enc(float f) {
    unsigned u = __float_as_uint(f);
    return (u & 0x80000000u) ? ~u : (u | 0x80000000u);
}
__device__ __forceinline__ float dec(unsigned k) {
    unsigned u = (k & 0x80000000u) ? (k & 0x7FFFFFFFu) : ~k;
    return __uint_as_float(u);
}

__global__ void init_k(unsigned* __restrict__ mn_k, unsigned* __restrict__ mx_k) {
    int i = blockIdx.x * blockDim.x + threadIdx.x;
    if (i < NSEG) {
        mn_k[i] = 0xFFFFFFFFu;  // max key (encodes "+inf")
        mx_k[i] = 0u;           // min key
    }
}

__device__ __forceinline__ void wave_reduce(float& mn, float& mx) {
#pragma unroll
    for (int off = 32; off; off >>= 1) {
        mn = fminf(mn, __shfl_xor(mn, off));
        mx = fmaxf(mx, __shfl_xor(mx, off));
    }
}

// Coalesced pass1: block = 256 threads, tile = 256 contiguous rows (4096 float4).
// Lane i reads float4 i -> 16B/lane consecutive, fully coalesced.
// seg is sorted, so seg[first]==seg[last] => whole tile one segment (~52% of tiles):
// private accumulate + 1 atomic pair per wave. Boundary tiles: per-iteration
// wave-segmented reduce with lane-0 register accumulator.
__global__ __launch_bounds__(256) void pass1(const float4* __restrict__ x4,
                                             const int* __restrict__ seg,
                                             unsigned* __restrict__ mn_k,
                                             unsigned* __restrict__ mx_k,
                                             int nrows) {
    const long n4 = (long)nrows * 16;
    const long base = (long)blockIdx.x * TF4;
    const int t = threadIdx.x;
    const int row0 = blockIdx.x * TROWS;
    const int rlast = min(row0 + TROWS, nrows) - 1;
    const int sf = seg[row0];
    const int sl = seg[rlast];

    if (sf == sl) {
        // single-segment tile: private accumulation, minimal VALU
        float lmin = INFINITY, lmax = -INFINITY;
#pragma unroll
        for (int i = 0; i < 16; ++i) {
            long f = base + (long)i * 256 + t;
            if (f < n4) {
                float4 v = x4[f];
                lmin = fminf(lmin, fminf(fminf(v.x, v.y), fminf(v.z, v.w)));
                lmax = fmaxf(lmax, fmaxf(fmaxf(v.x, v.y), fmaxf(v.z, v.w)));
            }
        }
        wave_reduce(lmin, lmax);
        if ((t & 63) == 0) {
            atomicMin(&mn_k[sf], enc(lmin));
            atomicMax(&mx_k[sf], enc(lmax));
        }
    } else {
        // boundary tile: wave-segmented per iteration, still coalesced
        float amin = INFINITY, amax = -INFINITY;
        int as = -1;  // lane-0 accumulator segment
#pragma unroll
        for (int i = 0; i < 16; ++i) {
            long f = base + (long)i * 256 + t;
            bool valid = f < n4;
            float lmin = INFINITY, lmax = -INFINITY;
            int s = -1;
            if (valid) {
                float4 v = x4[f];
                lmin = fminf(fminf(v.x, v.y), fminf(v.z, v.w));
                lmax = fmaxf(fmaxf(v.x, v.y), fmaxf(v.z, v.w));
                s = seg[(int)(f >> 4)];
            }
            int s0 = __shfl(s, 0);  // lane0 has smallest f -> valid if any lane is
            if (__all(s == s0 || !valid)) {
                if (s0 < 0) continue;  // whole wave past end
                wave_reduce(lmin, lmax);
                if ((t & 63) == 0) {
                    if (s0 != as) {
                        if (as >= 0) {
                            atomicMin(&mn_k[as], enc(amin));
                            atomicMax(&mx_k[as], enc(amax));
                        }
                        as = s0; amin = lmin; amax = lmax;
                    } else {
                        amin = fminf(amin, lmin);
                        amax = fmaxf(amax, lmax);
                    }
                }
            } else {
                // segment boundary inside this wave's 4 rows (rare): per-lane atomics
                if (valid) {
                    atomicMin(&mn_k[s], enc(lmin));
                    atomicMax(&mx_k[s], enc(lmax));
                }
            }
        }
        if ((t & 63) == 0 && as >= 0) {
            atomicMin(&mn_k[as], enc(amin));
            atomicMax(&mx_k[as], enc(amax));
        }
    }
}

__global__ void scalek(const unsigned* __restrict__ mn_k,
                       const unsigned* __restrict__ mx_k,
                       float2* __restrict__ prm) {
    int i = blockIdx.x * blockDim.x + threadIdx.x;
    if (i < NSEG) {
        float mn = dec(mn_k[i]);
        float mx = dec(mx_k[i]);
        float2 p;
        p.x = mn;
        p.y = 1.0f / (mx - mn + EPS);
        prm[i] = p;
    }
}

// One thread per float4; nontemporal store for out (never re-read).
__global__ __launch_bounds__(256) void pass2(const float4* __restrict__ x4,
                                             const int* __restrict__ seg,
                                             const float2* __restrict__ prm,
                                             nfloat4* __restrict__ out4,
                                             long n4) {
    long g = (long)blockIdx.x * 256 + threadIdx.x;
    if (g >= n4) return;
    int row = (int)(g >> 4);
    int s = seg[row];
    float2 p = prm[s];
    float4 v = x4[g];
    nfloat4 o;
    o.x = (v.x - p.x) * p.y;
    o.y = (v.y - p.x) * p.y;
    o.z = (v.z - p.x) * p.y;
    o.w = (v.w - p.x) * p.y;
    __builtin_nontemporal_store(o, &out4[g]);
}

extern "C" void kernel_launch(void* const* d_in, const int* in_sizes, int n_in,
                              void* d_out, int out_size, void* d_ws, size_t ws_size,
                              hipStream_t stream) {
    const float* x = (const float*)d_in[0];
    const int* seg = (const int*)d_in[1];
    float* out = (float*)d_out;

    const int nrows = in_sizes[1];       // N = 1,000,000
    const long n4 = (long)out_size / 4;  // float4 count

    unsigned* mn_k = (unsigned*)d_ws;     // [NSEG]
    unsigned* mx_k = mn_k + NSEG;         // [NSEG]
    float2* prm = (float2*)(mx_k + NSEG); // [NSEG]

    init_k<<<(NSEG + 255) / 256, 256, 0, stream>>>(mn_k, mx_k);

    int blocks1 = (nrows + TROWS - 1) / TROWS;
    pass1<<<blocks1, 256, 0, stream>>>((const float4*)x, seg, mn_k, mx_k, nrows);

    scalek<<<(NSEG + 255) / 256, 256, 0, stream>>>(mn_k, mx_k, prm);

    long blocks2 = (n4 + 255) / 256;
    pass2<<<(int)blocks2, 256, 0, stream>>>((const float4*)x, seg, prm,
                                            (nfloat4*)out, n4);
}